// Round 16
// baseline (216.411 us; speedup 1.0000x reference)
//
#include <hip/hip_runtime.h>
#include <stdint.h>

#define B_N 4096
#define T_N 8
#define DIN 4096
#define H2C 512
#define HC 256
#define NWG1 1024       // bmap slots: 128 per task residue (task t -> slots s with s%8==t)
#define NWG2 264
#define SPLITK1 4

typedef __attribute__((ext_vector_type(8))) short bf16x8;
typedef __attribute__((ext_vector_type(4))) float f32x4;

static __device__ __forceinline__ unsigned short f2bf(float f) {
    union { float f; uint32_t u; } v; v.f = f;
    uint32_t u = v.u;
    uint32_t r = (u + 0x7FFFu + ((u >> 16) & 1u)) >> 16;
    return (unsigned short)r;
}

static __device__ __forceinline__ float bf2f(uint32_t h) {
    union { uint32_t u; float f; } v; v.u = h << 16; return v.f;
}

static __device__ __forceinline__ uint32_t pk2(float a, float b) {
    uint32_t r;
    asm volatile("v_cvt_pk_bf16_f32 %0, %1, %2" : "=v"(r) : "v"(a), "v"(b));
    return r;
}

static __device__ __forceinline__ void gl2lds16(const unsigned short* g, unsigned short* l) {
    __builtin_amdgcn_global_load_lds(
        (const __attribute__((address_space(1))) unsigned int*)(g),
        (__attribute__((address_space(3))) unsigned int*)(l), 16, 0, 0);
}

static __device__ __forceinline__ int xcd_remap(int bid, int nwg) {
    int xcd = bid & 7, idx = bid >> 3;
    int q = nwg >> 3, r = nwg & 7;
    return (xcd < r ? xcd * (q + 1) : r * (q + 1) + (xcd - r) * q) + idx;
}

// ===== k_pre: [0] prep | [1..4096] trans W1 | [4097..4352] trans W2  (no X convert) =====
__launch_bounds__(256)
__global__ void k_pre(const float* __restrict__ W1, const float* __restrict__ W2,
                      const int* __restrict__ task_ids,
                      const float* __restrict__ temb, const float* __restrict__ Ww,
                      const float* __restrict__ bw,
                      unsigned short* __restrict__ W1t, unsigned short* __restrict__ W2t,
                      int* __restrict__ order, int* __restrict__ tiles, int* __restrict__ bmap,
                      int* __restrict__ tiles2, int* __restrict__ ntile2,
                      float* __restrict__ tb) {
    int blk = blockIdx.x, tid = threadIdx.x;
    if (blk == 0) {
        __shared__ unsigned long long wtot[4][2];
        __shared__ int lc[T_N], lseg[T_N], tb1p[T_N + 1], tb2p[T_N + 1];
        int lane = tid & 63, wv = tid >> 6;
        int4 a0 = *(const int4*)(task_ids + tid * 16);
        int4 a1 = *(const int4*)(task_ids + tid * 16 + 4);
        int4 a2 = *(const int4*)(task_ids + tid * 16 + 8);
        int4 a3 = *(const int4*)(task_ids + tid * 16 + 12);
        int myt[16] = {a0.x, a0.y, a0.z, a0.w, a1.x, a1.y, a1.z, a1.w,
                       a2.x, a2.y, a2.z, a2.w, a3.x, a3.y, a3.z, a3.w};
        unsigned long long ph0 = 0, ph1 = 0;
        #pragma unroll
        for (int i = 0; i < 16; ++i) {
            int t = myt[i];
            if (t < 4) ph0 += 1ull << (t * 16); else ph1 += 1ull << ((t - 4) * 16);
        }
        unsigned long long s0 = ph0, s1 = ph1;
        for (int o = 1; o < 64; o <<= 1) {
            unsigned long long u0 = __shfl_up(s0, o);
            unsigned long long u1 = __shfl_up(s1, o);
            if (lane >= o) { s0 += u0; s1 += u1; }
        }
        if (lane == 63) { wtot[wv][0] = s0; wtot[wv][1] = s1; }
        __syncthreads();
        unsigned long long e0 = s0 - ph0, e1 = s1 - ph1;
        for (int w2 = 0; w2 < wv; ++w2) { e0 += wtot[w2][0]; e1 += wtot[w2][1]; }
        if (tid == 0) {
            unsigned long long t0 = 0, t1 = 0;
            for (int w2 = 0; w2 < 4; ++w2) { t0 += wtot[w2][0]; t1 += wtot[w2][1]; }
            int s = 0;
            for (int t = 0; t < T_N; ++t) {
                int c = (int)((t < 4 ? (t0 >> (t * 16)) : (t1 >> ((t - 4) * 16))) & 0xFFFF);
                lc[t] = c; lseg[t] = s; s += c;
            }
            int q1 = 0, q2 = 0;
            for (int t = 0; t < T_N; ++t) {
                tb1p[t] = q1; tb2p[t] = q2;
                q1 += (lc[t] + 127) >> 7; q2 += (lc[t] + 15) >> 4;
            }
            tb1p[T_N] = q1; tb2p[T_N] = q2;
            ntile2[0] = q2;
        }
        __syncthreads();
        unsigned long long r0 = e0, r1 = e1;
        #pragma unroll
        for (int i = 0; i < 16; ++i) {
            int t = myt[i], rk;
            if (t < 4) { rk = (int)((r0 >> (t * 16)) & 0xFFFF); r0 += 1ull << (t * 16); }
            else { int u = t - 4; rk = (int)((r1 >> (u * 16)) & 0xFFFF); r1 += 1ull << (u * 16); }
            order[lseg[t] + rk] = tid * 16 + i;
        }
        int n1 = tb1p[T_N], n2 = tb2p[T_N];
        for (int e = tid; e < n1; e += 256) {
            int t = 0; while (e >= tb1p[t + 1]) ++t;
            int rr = (e - tb1p[t]) << 7;
            tiles[3 * e] = t; tiles[3 * e + 1] = lseg[t] + rr;
            int rem = lc[t] - rr; tiles[3 * e + 2] = rem < 128 ? rem : 128;
        }
        for (int e = tid; e < n2; e += 256) {
            int t = 0; while (e >= tb2p[t + 1]) ++t;
            int rr = (e - tb2p[t]) << 4;
            tiles2[3 * e] = t; tiles2[3 * e + 1] = lseg[t] + rr;
            int rem = lc[t] - rr; tiles2[3 * e + 2] = rem < 16 ? rem : 16;
        }
        for (int s = tid; s < NWG1; s += 256) {
            int t = s & 7, j = s >> 3;
            int base = tb1p[t], nt = tb1p[t + 1] - base;
            bmap[s] = (j < nt * 16) ? (((base + (j >> 4)) << 4) | (j & 15)) : -1;
        }
        __syncthreads();
        if (tid == 0) {   // overflow fixup (only if a task has >8 row-tiles)
            int freeslot = 0;
            for (int t = 0; t < T_N; ++t) {
                int base = tb1p[t], nt = tb1p[t + 1] - base;
                for (int j = 128; j < nt * 16; ++j) {
                    while (bmap[freeslot] >= 0) ++freeslot;
                    bmap[freeslot] = ((base + (j >> 4)) << 4) | (j & 15);
                }
            }
        }
        for (int t = wv; t < T_N; t += 4) {
            int m = lane & 3, hb = (lane >> 2) * 16;
            float s = 0.f;
            for (int h = 0; h < 16; ++h)
                s += temb[t * HC + hb + h] * Ww[((size_t)t * H2C + HC + hb + h) * 4 + m];
            for (int o = 4; o < 64; o <<= 1) s += __shfl_xor(s, o);
            if (lane < 4) tb[t * 4 + lane] = s + bw[t * 4 + lane];
        }
        return;
    }
    // ---- weight transpose [T][R][C] fp32 -> [T][C][R] bf16, 64x64 tiles (r8-proven) ----
    __shared__ float tile[64][65];
    const float* ip; unsigned short* op; int R, C, bx, by, t;
    if (blk < 4097) {
        int idx = blk - 1; bx = idx & 63; by = (idx >> 6) & 7; t = idx >> 9;
        R = DIN; C = H2C;
        ip = W1 + (size_t)t * R * C; op = W1t + (size_t)t * R * C;
    } else {
        int idx = blk - 4097; bx = idx & 7; by = (idx >> 3) & 3; t = idx >> 5;
        R = H2C; C = HC;
        ip = W2 + (size_t)t * R * C; op = W2t + (size_t)t * R * C;
    }
    int r0 = bx * 64, c0 = by * 64;
    int lr = tid >> 4, lc4 = (tid & 15) * 4;
    #pragma unroll
    for (int i = 0; i < 4; ++i) {
        float4 v = *(const float4*)&ip[(size_t)(r0 + lr + i * 16) * C + c0 + lc4];
        tile[lr + i * 16][lc4 + 0] = v.x;
        tile[lr + i * 16][lc4 + 1] = v.y;
        tile[lr + i * 16][lc4 + 2] = v.z;
        tile[lr + i * 16][lc4 + 3] = v.w;
    }
    __syncthreads();
    int r4 = (tid & 15) * 4;
    #pragma unroll
    for (int i = 0; i < 4; ++i) {
        int cc = i * 16 + (tid >> 4);
        uint2 wv;
        wv.x = (uint32_t)f2bf(tile[r4 + 0][cc]) | ((uint32_t)f2bf(tile[r4 + 1][cc]) << 16);
        wv.y = (uint32_t)f2bf(tile[r4 + 2][cc]) | ((uint32_t)f2bf(tile[r4 + 3][cc]) << 16);
        *(uint2*)&op[(size_t)(c0 + cc) * R + r0 + r4] = wv;
    }
}

// ===== GEMM1: fp32-A direct, 2-deep reg prefetch + counted-vmcnt raw barriers =====
// A: global fp32 -> regs (issued 2 iters ahead) -> cvt_pk -> swizzled ds_write (bf16).
// B: global_load_lds from W1t (pre-swizzled source, linear dest).
__launch_bounds__(256)
__global__ void k_gemm1(const float* __restrict__ f0, const float* __restrict__ f1,
                        const float* __restrict__ f2, const float* __restrict__ f3,
                        const unsigned short* __restrict__ Bt,
                        unsigned short* __restrict__ Cb16, const int* __restrict__ order,
                        const int* __restrict__ tiles, const int* __restrict__ bmap) {
    int e = bmap[blockIdx.x];
    if (e < 0) return;
    int tix = e >> 4, sub = e & 15;
    int ct = sub >> 2, kc = sub & 3;
    int t = tiles[3 * tix], prow = tiles[3 * tix + 1], rows = tiles[3 * tix + 2];
    int kb = kc * (DIN / SPLITK1);                // B-side K offset only
    const float* fsrc = (kc == 0) ? f0 : (kc == 1) ? f1 : (kc == 2) ? f2 : f3;

    __shared__ unsigned short lds[2][16384];      // [A:8192 | B:8192] shorts, 64 KB

    int tid = threadIdx.x, lane = tid & 63, w = tid >> 6;
    int wm = w >> 1, wn = w & 1;

    // A: fp32 source (within-modality k), LDS offset swizzled; both sides share XOR
    const float* srcA[4];
    int ldsA[4];
    #pragma unroll
    for (int i = 0; i < 4; ++i) {
        int gi = i * 256 + tid;
        int row = gi >> 3, g = gi & 7;
        int rl = row < rows ? row : rows - 1;
        srcA[i] = fsrc + (size_t)order[prow + rl] * 1024 + g * 8;
        ldsA[i] = row * 64 + ((g ^ (row & 7)) * 8);
    }
    // B: glds, pre-swizzled source granule
    const unsigned short* pB[4];
    #pragma unroll
    for (int j = 0; j < 4; ++j) {
        int row = j * 32 + (tid >> 3);
        int colg = (tid & 7) ^ (row & 7);
        pB[j] = Bt + ((size_t)t * H2C + ct * 128 + row) * DIN + kb + colg * 8;
    }

    float4 a0[2][4], a1[2][4];                    // two A register sets
    auto loadA = [&](int set, int k0) {
        #pragma unroll
        for (int i = 0; i < 4; ++i) {
            a0[set][i] = *(const float4*)(srcA[i] + k0);
            a1[set][i] = *(const float4*)(srcA[i] + k0 + 4);
        }
    };
    auto writeA = [&](int buf, int set) {
        #pragma unroll
        for (int i = 0; i < 4; ++i) {
            uint4 wv;
            wv.x = pk2(a0[set][i].x, a0[set][i].y); wv.y = pk2(a0[set][i].z, a0[set][i].w);
            wv.z = pk2(a1[set][i].x, a1[set][i].y); wv.w = pk2(a1[set][i].z, a1[set][i].w);
            *(uint4*)&lds[buf][ldsA[i]] = wv;
        }
    };
    auto stageB = [&](int buf, int it) {
        unsigned short* dB = &lds[buf][8192 + w * 512];
        #pragma unroll
        for (int j = 0; j < 4; ++j) gl2lds16(pB[j] + it * 64, dB + j * 2048);
    };

    f32x4 acc[4][4];
    #pragma unroll
    for (int m = 0; m < 4; ++m)
        #pragma unroll
        for (int n = 0; n < 4; ++n)
            acc[m][n] = (f32x4){0.f, 0.f, 0.f, 0.f};

    constexpr int NIT = 16;                       // 1024 floats / 64 per iter
    // prologue
    loadA(0, 0);
    stageB(0, 0);
    writeA(0, 0);                                 // compiler waits on set0 loads
    loadA(1, 64);                                 // set1 for it=1, flies ~1 iter
    __builtin_amdgcn_sched_barrier(0);
    asm volatile("s_waitcnt vmcnt(8) lgkmcnt(0)" ::: "memory");  // stageB(0) done; 8 A-loads fly
    __builtin_amdgcn_sched_barrier(0);
    __builtin_amdgcn_s_barrier();

    int cur = 0;
    for (int it = 0; it < NIT; ++it) {
        if (it + 1 < NIT) stageB(cur ^ 1, it + 1);            // 4 glds
        const unsigned short* As = &lds[cur][0];
        const unsigned short* Bs = As + 8192;
        #pragma unroll
        for (int ks = 0; ks < 2; ++ks) {
            int g = ks * 4 + (lane >> 4);
            bf16x8 af[4], bfv[4];
            #pragma unroll
            for (int m = 0; m < 4; ++m) {
                int row = wm * 64 + m * 16 + (lane & 15);
                af[m] = *(const bf16x8*)&As[row * 64 + ((g ^ (row & 7)) * 8)];
            }
            #pragma unroll
            for (int n = 0; n < 4; ++n) {
                int row = wn * 64 + n * 16 + (lane & 15);
                bfv[n] = *(const bf16x8*)&Bs[row * 64 + ((g ^ (row & 7)) * 8)];
            }
            #pragma unroll
            for (int m = 0; m < 4; ++m)
                #pragma unroll
                for (int n = 0; n < 4; ++n)
                    acc[m][n] = __builtin_amdgcn_mfma_f32_16x16x32_bf16(af[m], bfv[n], acc[m][n], 0, 0, 0);
        }
        if (it + 1 < NIT) {
            // A-loads for it+1 were issued a full iteration ago; 4 stageB glds are newest
            asm volatile("s_waitcnt vmcnt(4)" ::: "memory");
            __builtin_amdgcn_sched_barrier(0);
            writeA(cur ^ 1, (it + 1) & 1);
            if (it + 2 < NIT) {
                loadA((it + 2) & 1, (it + 2) * 64);           // 8 loads, fly 1 iter
                __builtin_amdgcn_sched_barrier(0);
                asm volatile("s_waitcnt vmcnt(8) lgkmcnt(0)" ::: "memory");  // stageB done
            } else {
                asm volatile("s_waitcnt vmcnt(0) lgkmcnt(0)" ::: "memory");
            }
            __builtin_amdgcn_sched_barrier(0);
            __builtin_amdgcn_s_barrier();
        }
        cur ^= 1;
    }

    unsigned short* Cb = Cb16 + (size_t)kc * B_N * H2C;
    #pragma unroll
    for (int m = 0; m < 4; ++m) {
        #pragma unroll
        for (int n = 0; n < 4; ++n) {
            int col = ct * 128 + wn * 64 + n * 16 + (lane & 15);
            #pragma unroll
            for (int j = 0; j < 4; ++j) {
                int row = wm * 64 + m * 16 + (lane >> 4) * 4 + j;
                if (row < rows)
                    Cb[(size_t)(prow + row) * H2C + col] = f2bf(acc[m][n][j]);
            }
        }
    }
}

// ===== GEMM2 fused (r8-proven): LN1+ReLU -> GEMM(512->256) -> LN2+ReLU -> wdot+softmax =====
__launch_bounds__(256)
__global__ void k_gemm2f(const unsigned short* __restrict__ h1p, const unsigned short* __restrict__ W2t,
                         const float* __restrict__ b1, const float* __restrict__ g1,
                         const float* __restrict__ be1,
                         const float* __restrict__ b2, const float* __restrict__ g2,
                         const float* __restrict__ be2,
                         const float* __restrict__ Ww, const float* __restrict__ tb,
                         const int* __restrict__ order,
                         const int* __restrict__ tiles2, const int* __restrict__ ntile2,
                         float* __restrict__ out) {
    __shared__ unsigned short Asm[16 * 512];      // 16 KB, swizzled bf16
    __shared__ unsigned short Bsm[2][256 * 32];   // 2 x 16 KB
    __shared__ float red[16][4][4];

    int id = xcd_remap(blockIdx.x, NWG2);
    if (id >= ntile2[0]) return;
    int t = tiles2[3 * id], prow = tiles2[3 * id + 1], rows = tiles2[3 * id + 2];
    int tid = threadIdx.x, lane = tid & 63, w = tid >> 6;

    // ---- prologue: LN1(sum 4 bf16 split-K partials + b1) + ReLU -> bf16 -> Asm ----
    {
        int r = tid >> 4;
        int rl = r < rows ? r : rows - 1;
        int c0 = (tid & 15) * 32;
        const unsigned short* p0 = h1p + (size_t)(prow + rl) * H2C + c0;
        const float* pb = b1 + t * H2C + c0;
        float x[32];
        float s = 0.f, sq = 0.f;
        #pragma unroll
        for (int i = 0; i < 32; i += 8) {
            uint4 u0 = *(const uint4*)(p0 + i);
            uint4 u1 = *(const uint4*)(p0 + (size_t)B_N * H2C + i);
            uint4 u2 = *(const uint4*)(p0 + (size_t)2 * B_N * H2C + i);
            uint4 u3 = *(const uint4*)(p0 + (size_t)3 * B_N * H2C + i);
            uint32_t w0[4] = {u0.x, u0.y, u0.z, u0.w};
            uint32_t w1[4] = {u1.x, u1.y, u1.z, u1.w};
            uint32_t w2[4] = {u2.x, u2.y, u2.z, u2.w};
            uint32_t w3[4] = {u3.x, u3.y, u3.z, u3.w};
            float4 c0v = *(const float4*)(pb + i);
            float4 c1v = *(const float4*)(pb + i + 4);
            float cv[8] = {c0v.x, c0v.y, c0v.z, c0v.w, c1v.x, c1v.y, c1v.z, c1v.w};
            #pragma unroll
            for (int q = 0; q < 4; ++q) {
                float v0 = bf2f(w0[q] & 0xFFFFu) + bf2f(w1[q] & 0xFFFFu)
                         + bf2f(w2[q] & 0xFFFFu) + bf2f(w3[q] & 0xFFFFu) + cv[2 * q];
                float v1 = bf2f(w0[q] >> 16) + bf2f(w1[q] >> 16)
                         + bf2f(w2[q] >> 16) + bf2f(w3[q] >> 16) + cv[2 * q + 1];
                x[i + 2 * q] = v0; x[i + 2 * q + 1] = v1;
                s += v0 + v1; sq += v0 * v0 + v1 * v1;
            }
        }
        #pragma unroll
        for (int o = 1; o < 16; o <<= 1) { s += __shfl_xor(s, o); sq += __shfl_xor(sq, o); }
        float mean = s * (1.f / H2C);
        float var = sq * (1.f / H2C) - mean * mean;
        float rstd = rsqrtf(var + 1e-5f);
        const float* pg = g1 + t * H2C + c0;
        const float* pe = be1 + t * H2C + c0;
        #pragma unroll
        for (int i = 0; i < 32; i += 8) {
            unsigned short y[8];
            #pragma unroll
            for (int q = 0; q < 8; q += 4) {
                float4 gv = *(const float4*)(pg + i + q);
                float4 ev = *(const float4*)(pe + i + q);
                y[q + 0] = f2bf(fmaxf((x[i + q + 0] - mean) * rstd * gv.x + ev.x, 0.f));
                y[q + 1] = f2bf(fmaxf((x[i + q + 1] - mean) * rstd * gv.y + ev.y, 0.f));
                y[q + 2] = f2bf(fmaxf((x[i + q + 2] - mean) * rstd * gv.z + ev.z, 0.f));
                y[q + 3] = f2bf(fmaxf((x[i + q + 3] - mean) * rstd * gv.w + ev.w, 0.f));
            }
            uint4 wv;
            wv.x = (uint32_t)y[0] | ((uint32_t)y[1] << 16);
            wv.y = (uint32_t)y[2] | ((uint32_t)y[3] << 16);
            wv.z = (uint32_t)y[4] | ((uint32_t)y[5] << 16);
            wv.w = (uint32_t)y[6] | ((uint32_t)y[7] << 16);
            int g = (c0 + i) >> 3;
            *(uint4*)&Asm[r * 512 + ((g ^ (r & 7)) * 8)] = wv;
        }
    }

    auto stageB = [&](int buf, int it) {
        #pragma unroll
        for (int j = 0; j < 4; ++j) {
            int G = j * 256 + tid;
            int row = G >> 2, g = G & 3;
            int colg = g ^ (row & 3);
            gl2lds16(W2t + ((size_t)t * HC + row) * H2C + it * 32 + colg * 8,
                     &Bsm[buf][(j * 256 + w * 64) * 8]);
        }
    };

    stageB(0, 0);
    __syncthreads();

    f32x4 acc[4];
    #pragma unroll
    for (int n = 0; n < 4; ++n) acc[n] = (f32x4){0.f, 0.f, 0.f, 0.f};

    for (int it = 0; it < 16; ++it) {
        if (it + 1 < 16) stageB((it + 1) & 1, it + 1);
        const unsigned short* Bs = &Bsm[it & 1][0];
        int g = lane >> 4;
        int arow = lane & 15;
        bf16x8 af = *(const bf16x8*)&Asm[arow * 512 + (((it * 4 + g) ^ (arow & 7)) * 8)];
        #pragma unroll
        for (int n = 0; n < 4; ++n) {
            int brow = w * 64 + n * 16 + arow;
            bf16x8 bv = *(const bf16x8*)&Bs[brow * 32 + ((g ^ (brow & 3)) * 8)];
            acc[n] = __builtin_amdgcn_mfma_f32_16x16x32_bf16(af, bv, acc[n], 0, 0, 0);
        }
        __syncthreads();
    }

    // ---- epilogue: LN2 + ReLU + weight-net dot + softmax + scatter ----
    float b2v[4], g2v[4], e2v[4];
    float4 wv[4];
    #pragma unroll
    for (int n = 0; n < 4; ++n) {
        int col = w * 64 + n * 16 + (lane & 15);
        b2v[n] = b2[t * HC + col];
        g2v[n] = g2[t * HC + col];
        e2v[n] = be2[t * HC + col];
        wv[n] = *(const float4*)&Ww[((size_t)t * H2C + col) * 4];
    }
    float s4[4], q4[4];
    #pragma unroll
    for (int j = 0; j < 4; ++j) {
        float s = 0.f, sq = 0.f;
        #pragma unroll
        for (int n = 0; n < 4; ++n) {
            float xv = acc[n][j] + b2v[n];
            s += xv; sq += xv * xv;
        }
        #pragma unroll
        for (int o = 1; o < 16; o <<= 1) { s += __shfl_xor(s, o); sq += __shfl_xor(sq, o); }
        s4[j] = s; q4[j] = sq;
    }
    if ((lane & 15) == 0) {
        #pragma unroll
        for (int j = 0; j < 4; ++j) {
            int r = (lane >> 4) * 4 + j;
            red[r][w][0] = s4[j];
            red[r][w][1] = q4[j];
        }
    }
    __syncthreads();
    float mean[4], rstd[4];
    #pragma unroll
    for (int j = 0; j < 4; ++j) {
        int r = (lane >> 4) * 4 + j;
        float S = red[r][0][0] + red[r][1][0] + red[r][2][0] + red[r][3][0];
        float SQ = red[r][0][1] + red[r][1][1] + red[r][2][1] + red[r][3][1];
        mean[j] = S * (1.f / HC);
        float var = SQ * (1.f / HC) - mean[j] * mean[j];
        rstd[j] = rsqrtf(var + 1e-5f);
    }
    float p[4][4];
    #pragma unroll
    for (int j = 0; j < 4; ++j) {
        p[j][0] = 0.f; p[j][1] = 0.f; p[j][2] = 0.f; p[j][3] = 0.f;
        #pragma unroll
        for (int n = 0; n < 4; ++n) {
            float yv = fmaxf((acc[n][j] + b2v[n] - mean[j]) * rstd[j] * g2v[n] + e2v[n], 0.f);
            p[j][0] += yv * wv[n].x; p[j][1] += yv * wv[n].y;
            p[j][2] += yv * wv[n].z; p[j][3] += yv * wv[n].w;
        }
        #pragma unroll
        for (int m = 0; m < 4; ++m)
            #pragma unroll
            for (int o = 1; o < 16; o <<= 1) p[j][m] += __shfl_xor(p[j][m], o);
    }
    __syncthreads();
    if ((lane & 15) == 0) {
        #pragma unroll
        for (int j = 0; j < 4; ++j) {
            int r = (lane >> 4) * 4 + j;
            red[r][w][0] = p[j][0]; red[r][w][1] = p[j][1];
            red[r][w][2] = p[j][2]; red[r][w][3] = p[j][3];
        }
    }
    __syncthreads();
    if (tid < 16 && tid < rows) {
        float raw[4];
        #pragma unroll
        for (int m = 0; m < 4; ++m)
            raw[m] = red[tid][0][m] + red[tid][1][m] + red[tid][2][m] + red[tid][3][m] + tb[t * 4 + m];
        float mx = fmaxf(fmaxf(raw[0], raw[1]), fmaxf(raw[2], raw[3]));
        float e0 = expf(raw[0] - mx), e1 = expf(raw[1] - mx);
        float e2 = expf(raw[2] - mx), e3 = expf(raw[3] - mx);
        float si = 1.f / (e0 + e1 + e2 + e3);
        *(float4*)(out + (size_t)order[prow + tid] * 4) = make_float4(e0 * si, e1 * si, e2 * si, e3 * si);
    }
}

extern "C" void kernel_launch(void* const* d_in, const int* in_sizes, int n_in,
                              void* d_out, int out_size, void* d_ws, size_t ws_size,
                              hipStream_t stream) {
    const float* f0 = (const float*)d_in[0];
    const float* f1 = (const float*)d_in[1];
    const float* f2 = (const float*)d_in[2];
    const float* f3 = (const float*)d_in[3];
    const float* W1 = (const float*)d_in[4];
    const float* b1 = (const float*)d_in[5];
    const float* g1 = (const float*)d_in[6];
    const float* be1 = (const float*)d_in[7];
    const float* W2 = (const float*)d_in[8];
    const float* b2 = (const float*)d_in[9];
    const float* g2 = (const float*)d_in[10];
    const float* be2 = (const float*)d_in[11];
    const float* temb = (const float*)d_in[12];
    const float* Ww = (const float*)d_in[13];
    const float* bw = (const float*)d_in[14];
    const int* task_ids = (const int*)d_in[15];
    float* out = (float*)d_out;

    char* ws = (char*)d_ws;
    size_t off = 0;
    auto walloc = [&](size_t bytes) -> void* {
        void* p = ws + off;
        off = (off + bytes + 255) & ~(size_t)255;
        return p;
    };
    float* tb = (float*)walloc(128);
    int* tiles = (int*)walloc(64 * 3 * 4);
    int* bmap = (int*)walloc(NWG1 * 4);
    int* tiles2 = (int*)walloc(272 * 3 * 4);
    int* ntile2 = (int*)walloc(4);
    int* order = (int*)walloc((size_t)B_N * 4);
    unsigned short* W1t = (unsigned short*)walloc((size_t)T_N * H2C * DIN * 2);
    unsigned short* W2t = (unsigned short*)walloc((size_t)T_N * HC * H2C * 2);
    unsigned short* h1p = (unsigned short*)walloc((size_t)SPLITK1 * B_N * H2C * 2);

    k_pre<<<4353, 256, 0, stream>>>(W1, W2, task_ids, temb, Ww, bw,
                                    W1t, W2t, order, tiles, bmap, tiles2, ntile2, tb);
    k_gemm1<<<NWG1, 256, 0, stream>>>(f0, f1, f2, f3, W1t, h1p, order, tiles, bmap);
    k_gemm2f<<<NWG2, 256, 0, stream>>>(h1p, W2t, b1, g1, be1, b2, g2, be2, Ww, tb,
                                       order, tiles2, ntile2, out);
}

// Round 17
// 78.112 us; speedup vs baseline: 2.7705x; 2.7705x over previous
//
#include <hip/hip_runtime.h>
#include <stdint.h>

#define B_N 4096
#define T_N 8
#define DIN 4096
#define H2C 512
#define HC 256
#define NWG1 1024       // bmap slots: 128 per task residue (task t -> slots s with s%8==t)
#define NWG2 264
#define SPLITK1 4

typedef __attribute__((ext_vector_type(8))) short bf16x8;
typedef __attribute__((ext_vector_type(4))) float f32x4;

static __device__ __forceinline__ unsigned short f2bf(float f) {
    union { float f; uint32_t u; } v; v.f = f;
    uint32_t u = v.u;
    uint32_t r = (u + 0x7FFFu + ((u >> 16) & 1u)) >> 16;
    return (unsigned short)r;
}

static __device__ __forceinline__ float bf2f(uint32_t h) {
    union { uint32_t u; float f; } v; v.u = h << 16; return v.f;
}

static __device__ __forceinline__ uint32_t pk2(float a, float b) {
    uint32_t r;
    asm volatile("v_cvt_pk_bf16_f32 %0, %1, %2" : "=v"(r) : "v"(a), "v"(b));
    return r;
}

static __device__ __forceinline__ void gl2lds16(const unsigned short* g, unsigned short* l) {
    __builtin_amdgcn_global_load_lds(
        (const __attribute__((address_space(1))) unsigned int*)(g),
        (__attribute__((address_space(3))) unsigned int*)(l), 16, 0, 0);
}

static __device__ __forceinline__ int xcd_remap(int bid, int nwg) {
    int xcd = bid & 7, idx = bid >> 3;
    int q = nwg >> 3, r = nwg & 7;
    return (xcd < r ? xcd * (q + 1) : r * (q + 1) + (xcd - r) * q) + idx;
}

// ===== k_pre: [0] prep | [1..4096] trans W1 | [4097..4352] trans W2  (no X convert) =====
__launch_bounds__(256)
__global__ void k_pre(const float* __restrict__ W1, const float* __restrict__ W2,
                      const int* __restrict__ task_ids,
                      const float* __restrict__ temb, const float* __restrict__ Ww,
                      const float* __restrict__ bw,
                      unsigned short* __restrict__ W1t, unsigned short* __restrict__ W2t,
                      int* __restrict__ order, int* __restrict__ tiles, int* __restrict__ bmap,
                      int* __restrict__ tiles2, int* __restrict__ ntile2,
                      float* __restrict__ tb) {
    int blk = blockIdx.x, tid = threadIdx.x;
    if (blk == 0) {
        __shared__ unsigned long long wtot[4][2];
        __shared__ int lc[T_N], lseg[T_N], tb1p[T_N + 1], tb2p[T_N + 1];
        int lane = tid & 63, wv = tid >> 6;
        int4 a0 = *(const int4*)(task_ids + tid * 16);
        int4 a1 = *(const int4*)(task_ids + tid * 16 + 4);
        int4 a2 = *(const int4*)(task_ids + tid * 16 + 8);
        int4 a3 = *(const int4*)(task_ids + tid * 16 + 12);
        int myt[16] = {a0.x, a0.y, a0.z, a0.w, a1.x, a1.y, a1.z, a1.w,
                       a2.x, a2.y, a2.z, a2.w, a3.x, a3.y, a3.z, a3.w};
        unsigned long long ph0 = 0, ph1 = 0;
        #pragma unroll
        for (int i = 0; i < 16; ++i) {
            int t = myt[i];
            if (t < 4) ph0 += 1ull << (t * 16); else ph1 += 1ull << ((t - 4) * 16);
        }
        unsigned long long s0 = ph0, s1 = ph1;
        for (int o = 1; o < 64; o <<= 1) {
            unsigned long long u0 = __shfl_up(s0, o);
            unsigned long long u1 = __shfl_up(s1, o);
            if (lane >= o) { s0 += u0; s1 += u1; }
        }
        if (lane == 63) { wtot[wv][0] = s0; wtot[wv][1] = s1; }
        __syncthreads();
        unsigned long long e0 = s0 - ph0, e1 = s1 - ph1;
        for (int w2 = 0; w2 < wv; ++w2) { e0 += wtot[w2][0]; e1 += wtot[w2][1]; }
        if (tid == 0) {
            unsigned long long t0 = 0, t1 = 0;
            for (int w2 = 0; w2 < 4; ++w2) { t0 += wtot[w2][0]; t1 += wtot[w2][1]; }
            int s = 0;
            for (int t = 0; t < T_N; ++t) {
                int c = (int)((t < 4 ? (t0 >> (t * 16)) : (t1 >> ((t - 4) * 16))) & 0xFFFF);
                lc[t] = c; lseg[t] = s; s += c;
            }
            int q1 = 0, q2 = 0;
            for (int t = 0; t < T_N; ++t) {
                tb1p[t] = q1; tb2p[t] = q2;
                q1 += (lc[t] + 127) >> 7; q2 += (lc[t] + 15) >> 4;
            }
            tb1p[T_N] = q1; tb2p[T_N] = q2;
            ntile2[0] = q2;
        }
        __syncthreads();
        unsigned long long r0 = e0, r1 = e1;
        #pragma unroll
        for (int i = 0; i < 16; ++i) {
            int t = myt[i], rk;
            if (t < 4) { rk = (int)((r0 >> (t * 16)) & 0xFFFF); r0 += 1ull << (t * 16); }
            else { int u = t - 4; rk = (int)((r1 >> (u * 16)) & 0xFFFF); r1 += 1ull << (u * 16); }
            order[lseg[t] + rk] = tid * 16 + i;
        }
        int n1 = tb1p[T_N], n2 = tb2p[T_N];
        for (int e = tid; e < n1; e += 256) {
            int t = 0; while (e >= tb1p[t + 1]) ++t;
            int rr = (e - tb1p[t]) << 7;
            tiles[3 * e] = t; tiles[3 * e + 1] = lseg[t] + rr;
            int rem = lc[t] - rr; tiles[3 * e + 2] = rem < 128 ? rem : 128;
        }
        for (int e = tid; e < n2; e += 256) {
            int t = 0; while (e >= tb2p[t + 1]) ++t;
            int rr = (e - tb2p[t]) << 4;
            tiles2[3 * e] = t; tiles2[3 * e + 1] = lseg[t] + rr;
            int rem = lc[t] - rr; tiles2[3 * e + 2] = rem < 16 ? rem : 16;
        }
        for (int s = tid; s < NWG1; s += 256) {
            int t = s & 7, j = s >> 3;
            int base = tb1p[t], nt = tb1p[t + 1] - base;
            bmap[s] = (j < nt * 16) ? (((base + (j >> 4)) << 4) | (j & 15)) : -1;
        }
        __syncthreads();
        if (tid == 0) {   // overflow fixup (only if a task has >8 row-tiles)
            int freeslot = 0;
            for (int t = 0; t < T_N; ++t) {
                int base = tb1p[t], nt = tb1p[t + 1] - base;
                for (int j = 128; j < nt * 16; ++j) {
                    while (bmap[freeslot] >= 0) ++freeslot;
                    bmap[freeslot] = ((base + (j >> 4)) << 4) | (j & 15);
                }
            }
        }
        for (int t = wv; t < T_N; t += 4) {
            int m = lane & 3, hb = (lane >> 2) * 16;
            float s = 0.f;
            for (int h = 0; h < 16; ++h)
                s += temb[t * HC + hb + h] * Ww[((size_t)t * H2C + HC + hb + h) * 4 + m];
            for (int o = 4; o < 64; o <<= 1) s += __shfl_xor(s, o);
            if (lane < 4) tb[t * 4 + lane] = s + bw[t * 4 + lane];
        }
        return;
    }
    // ---- weight transpose [T][R][C] fp32 -> [T][C][R] bf16, 64x64 tiles (r8-proven) ----
    __shared__ float tile[64][65];
    const float* ip; unsigned short* op; int R, C, bx, by, t;
    if (blk < 4097) {
        int idx = blk - 1; bx = idx & 63; by = (idx >> 6) & 7; t = idx >> 9;
        R = DIN; C = H2C;
        ip = W1 + (size_t)t * R * C; op = W1t + (size_t)t * R * C;
    } else {
        int idx = blk - 4097; bx = idx & 7; by = (idx >> 3) & 3; t = idx >> 5;
        R = H2C; C = HC;
        ip = W2 + (size_t)t * R * C; op = W2t + (size_t)t * R * C;
    }
    int r0 = bx * 64, c0 = by * 64;
    int lr = tid >> 4, lc4 = (tid & 15) * 4;
    #pragma unroll
    for (int i = 0; i < 4; ++i) {
        float4 v = *(const float4*)&ip[(size_t)(r0 + lr + i * 16) * C + c0 + lc4];
        tile[lr + i * 16][lc4 + 0] = v.x;
        tile[lr + i * 16][lc4 + 1] = v.y;
        tile[lr + i * 16][lc4 + 2] = v.z;
        tile[lr + i * 16][lc4 + 3] = v.w;
    }
    __syncthreads();
    int r4 = (tid & 15) * 4;
    #pragma unroll
    for (int i = 0; i < 4; ++i) {
        int cc = i * 16 + (tid >> 4);
        uint2 wv;
        wv.x = (uint32_t)f2bf(tile[r4 + 0][cc]) | ((uint32_t)f2bf(tile[r4 + 1][cc]) << 16);
        wv.y = (uint32_t)f2bf(tile[r4 + 2][cc]) | ((uint32_t)f2bf(tile[r4 + 3][cc]) << 16);
        *(uint2*)&op[(size_t)(c0 + cc) * R + r0 + r4] = wv;
    }
}

// ===== GEMM1: fp32-A direct, 2 NAMED reg sets (rule #20), counted-vmcnt raw barriers =====
__launch_bounds__(256)
__global__ void k_gemm1(const float* __restrict__ f0, const float* __restrict__ f1,
                        const float* __restrict__ f2, const float* __restrict__ f3,
                        const unsigned short* __restrict__ Bt,
                        unsigned short* __restrict__ Cb16, const int* __restrict__ order,
                        const int* __restrict__ tiles, const int* __restrict__ bmap) {
    int e = bmap[blockIdx.x];
    if (e < 0) return;
    int tix = e >> 4, sub = e & 15;
    int ct = sub >> 2, kc = sub & 3;
    int t = tiles[3 * tix], prow = tiles[3 * tix + 1], rows = tiles[3 * tix + 2];
    int kb = kc * (DIN / SPLITK1);                // B-side K offset only
    const float* fsrc = (kc == 0) ? f0 : (kc == 1) ? f1 : (kc == 2) ? f2 : f3;

    __shared__ unsigned short lds[2][16384];      // [A:8192 | B:8192] shorts, 64 KB

    int tid = threadIdx.x, lane = tid & 63, w = tid >> 6;
    int wm = w >> 1, wn = w & 1;

    const float* srcA[4];
    int ldsA[4];
    #pragma unroll
    for (int i = 0; i < 4; ++i) {
        int gi = i * 256 + tid;
        int row = gi >> 3, g = gi & 7;
        int rl = row < rows ? row : rows - 1;
        srcA[i] = fsrc + (size_t)order[prow + rl] * 1024 + g * 8;
        ldsA[i] = row * 64 + ((g ^ (row & 7)) * 8);
    }
    const unsigned short* pB[4];
    #pragma unroll
    for (int j = 0; j < 4; ++j) {
        int row = j * 32 + (tid >> 3);
        int colg = (tid & 7) ^ (row & 7);
        pB[j] = Bt + ((size_t)t * H2C + ct * 128 + row) * DIN + kb + colg * 8;
    }

    // TWO statically-named A register sets (no runtime indexing -> no scratch)
    float4 xA0[4], xA1[4];                        // set A
    float4 yB0[4], yB1[4];                        // set B

    auto loadSetA = [&](int k0) {
        #pragma unroll
        for (int i = 0; i < 4; ++i) {
            xA0[i] = *(const float4*)(srcA[i] + k0);
            xA1[i] = *(const float4*)(srcA[i] + k0 + 4);
        }
    };
    auto loadSetB = [&](int k0) {
        #pragma unroll
        for (int i = 0; i < 4; ++i) {
            yB0[i] = *(const float4*)(srcA[i] + k0);
            yB1[i] = *(const float4*)(srcA[i] + k0 + 4);
        }
    };
    auto writeSetA = [&](int buf) {
        #pragma unroll
        for (int i = 0; i < 4; ++i) {
            uint4 wv;
            wv.x = pk2(xA0[i].x, xA0[i].y); wv.y = pk2(xA0[i].z, xA0[i].w);
            wv.z = pk2(xA1[i].x, xA1[i].y); wv.w = pk2(xA1[i].z, xA1[i].w);
            *(uint4*)&lds[buf][ldsA[i]] = wv;
        }
    };
    auto writeSetB = [&](int buf) {
        #pragma unroll
        for (int i = 0; i < 4; ++i) {
            uint4 wv;
            wv.x = pk2(yB0[i].x, yB0[i].y); wv.y = pk2(yB0[i].z, yB0[i].w);
            wv.z = pk2(yB1[i].x, yB1[i].y); wv.w = pk2(yB1[i].z, yB1[i].w);
            *(uint4*)&lds[buf][ldsA[i]] = wv;
        }
    };
    auto stageB = [&](int buf, int it) {
        unsigned short* dB = &lds[buf][8192 + w * 512];
        #pragma unroll
        for (int j = 0; j < 4; ++j) gl2lds16(pB[j] + it * 64, dB + j * 2048);
    };

    f32x4 acc[4][4];
    #pragma unroll
    for (int m = 0; m < 4; ++m)
        #pragma unroll
        for (int n = 0; n < 4; ++n)
            acc[m][n] = (f32x4){0.f, 0.f, 0.f, 0.f};

    auto compute = [&](int buf) {
        const unsigned short* As = &lds[buf][0];
        const unsigned short* Bs = As + 8192;
        #pragma unroll
        for (int ks = 0; ks < 2; ++ks) {
            int g = ks * 4 + (lane >> 4);
            bf16x8 af[4], bfv[4];
            #pragma unroll
            for (int m = 0; m < 4; ++m) {
                int row = wm * 64 + m * 16 + (lane & 15);
                af[m] = *(const bf16x8*)&As[row * 64 + ((g ^ (row & 7)) * 8)];
            }
            #pragma unroll
            for (int n = 0; n < 4; ++n) {
                int row = wn * 64 + n * 16 + (lane & 15);
                bfv[n] = *(const bf16x8*)&Bs[row * 64 + ((g ^ (row & 7)) * 8)];
            }
            #pragma unroll
            for (int m = 0; m < 4; ++m)
                #pragma unroll
                for (int n = 0; n < 4; ++n)
                    acc[m][n] = __builtin_amdgcn_mfma_f32_16x16x32_bf16(af[m], bfv[n], acc[m][n], 0, 0, 0);
        }
    };

    // ---- prologue: buf0 <- it0 (set A); set B loads (it1) in flight ----
    loadSetA(0);
    stageB(0, 0);
    writeSetA(0);                                 // compiler waits set-A loads only
    loadSetB(64);
    __builtin_amdgcn_sched_barrier(0);
    asm volatile("s_waitcnt vmcnt(8) lgkmcnt(0)" ::: "memory");   // stageB(0)+ds_writes done; 8 B-set loads fly
    __builtin_amdgcn_sched_barrier(0);
    __builtin_amdgcn_s_barrier();

    // ---- 7 pairs: iters 0..13 ----
    #pragma unroll 1
    for (int p = 0; p < 7; ++p) {
        int it0 = 2 * p;
        // even sub-iter: compute buf0 (it0); prepare buf1 (it0+1)
        stageB(1, it0 + 1);
        compute(0);
        asm volatile("s_waitcnt vmcnt(4)" ::: "memory");          // set-B loads landed
        __builtin_amdgcn_sched_barrier(0);
        writeSetB(1);
        loadSetA((it0 + 2) * 64);
        __builtin_amdgcn_sched_barrier(0);
        asm volatile("s_waitcnt vmcnt(8) lgkmcnt(0)" ::: "memory"); // stageB(1) done; 8 A-set fly
        __builtin_amdgcn_sched_barrier(0);
        __builtin_amdgcn_s_barrier();
        // odd sub-iter: compute buf1 (it0+1); prepare buf0 (it0+2)
        stageB(0, it0 + 2);
        compute(1);
        asm volatile("s_waitcnt vmcnt(4)" ::: "memory");          // set-A loads landed
        __builtin_amdgcn_sched_barrier(0);
        writeSetA(0);
        loadSetB((it0 + 3) * 64);
        __builtin_amdgcn_sched_barrier(0);
        asm volatile("s_waitcnt vmcnt(8) lgkmcnt(0)" ::: "memory"); // stageB(0) done; 8 B-set fly
        __builtin_amdgcn_sched_barrier(0);
        __builtin_amdgcn_s_barrier();
    }
    // ---- epilogue: it=14 (buf0), it=15 (buf1) ----
    stageB(1, 15);
    compute(0);
    asm volatile("s_waitcnt vmcnt(4)" ::: "memory");
    __builtin_amdgcn_sched_barrier(0);
    writeSetB(1);
    __builtin_amdgcn_sched_barrier(0);
    asm volatile("s_waitcnt vmcnt(0) lgkmcnt(0)" ::: "memory");
    __builtin_amdgcn_sched_barrier(0);
    __builtin_amdgcn_s_barrier();
    compute(1);

    unsigned short* Cb = Cb16 + (size_t)kc * B_N * H2C;
    #pragma unroll
    for (int m = 0; m < 4; ++m) {
        #pragma unroll
        for (int n = 0; n < 4; ++n) {
            int col = ct * 128 + wn * 64 + n * 16 + (lane & 15);
            #pragma unroll
            for (int j = 0; j < 4; ++j) {
                int row = wm * 64 + m * 16 + (lane >> 4) * 4 + j;
                if (row < rows)
                    Cb[(size_t)(prow + row) * H2C + col] = f2bf(acc[m][n][j]);
            }
        }
    }
}

// ===== GEMM2 fused (r8-proven): LN1+ReLU -> GEMM(512->256) -> LN2+ReLU -> wdot+softmax =====
__launch_bounds__(256)
__global__ void k_gemm2f(const unsigned short* __restrict__ h1p, const unsigned short* __restrict__ W2t,
                         const float* __restrict__ b1, const float* __restrict__ g1,
                         const float* __restrict__ be1,
                         const float* __restrict__ b2, const float* __restrict__ g2,
                         const float* __restrict__ be2,
                         const float* __restrict__ Ww, const float* __restrict__ tb,
                         const int* __restrict__ order,
                         const int* __restrict__ tiles2, const int* __restrict__ ntile2,
                         float* __restrict__ out) {
    __shared__ unsigned short Asm[16 * 512];      // 16 KB, swizzled bf16
    __shared__ unsigned short Bsm[2][256 * 32];   // 2 x 16 KB
    __shared__ float red[16][4][4];

    int id = xcd_remap(blockIdx.x, NWG2);
    if (id >= ntile2[0]) return;
    int t = tiles2[3 * id], prow = tiles2[3 * id + 1], rows = tiles2[3 * id + 2];
    int tid = threadIdx.x, lane = tid & 63, w = tid >> 6;

    // ---- prologue: LN1(sum 4 bf16 split-K partials + b1) + ReLU -> bf16 -> Asm ----
    {
        int r = tid >> 4;
        int rl = r < rows ? r : rows - 1;
        int c0 = (tid & 15) * 32;
        const unsigned short* p0 = h1p + (size_t)(prow + rl) * H2C + c0;
        const float* pb = b1 + t * H2C + c0;
        float x[32];
        float s = 0.f, sq = 0.f;
        #pragma unroll
        for (int i = 0; i < 32; i += 8) {
            uint4 u0 = *(const uint4*)(p0 + i);
            uint4 u1 = *(const uint4*)(p0 + (size_t)B_N * H2C + i);
            uint4 u2 = *(const uint4*)(p0 + (size_t)2 * B_N * H2C + i);
            uint4 u3 = *(const uint4*)(p0 + (size_t)3 * B_N * H2C + i);
            uint32_t w0[4] = {u0.x, u0.y, u0.z, u0.w};
            uint32_t w1[4] = {u1.x, u1.y, u1.z, u1.w};
            uint32_t w2[4] = {u2.x, u2.y, u2.z, u2.w};
            uint32_t w3[4] = {u3.x, u3.y, u3.z, u3.w};
            float4 c0v = *(const float4*)(pb + i);
            float4 c1v = *(const float4*)(pb + i + 4);
            float cv[8] = {c0v.x, c0v.y, c0v.z, c0v.w, c1v.x, c1v.y, c1v.z, c1v.w};
            #pragma unroll
            for (int q = 0; q < 4; ++q) {
                float v0 = bf2f(w0[q] & 0xFFFFu) + bf2f(w1[q] & 0xFFFFu)
                         + bf2f(w2[q] & 0xFFFFu) + bf2f(w3[q] & 0xFFFFu) + cv[2 * q];
                float v1 = bf2f(w0[q] >> 16) + bf2f(w1[q] >> 16)
                         + bf2f(w2[q] >> 16) + bf2f(w3[q] >> 16) + cv[2 * q + 1];
                x[i + 2 * q] = v0; x[i + 2 * q + 1] = v1;
                s += v0 + v1; sq += v0 * v0 + v1 * v1;
            }
        }
        #pragma unroll
        for (int o = 1; o < 16; o <<= 1) { s += __shfl_xor(s, o); sq += __shfl_xor(sq, o); }
        float mean = s * (1.f / H2C);
        float var = sq * (1.f / H2C) - mean * mean;
        float rstd = rsqrtf(var + 1e-5f);
        const float* pg = g1 + t * H2C + c0;
        const float* pe = be1 + t * H2C + c0;
        #pragma unroll
        for (int i = 0; i < 32; i += 8) {
            unsigned short y[8];
            #pragma unroll
            for (int q = 0; q < 8; q += 4) {
                float4 gv = *(const float4*)(pg + i + q);
                float4 ev = *(const float4*)(pe + i + q);
                y[q + 0] = f2bf(fmaxf((x[i + q + 0] - mean) * rstd * gv.x + ev.x, 0.f));
                y[q + 1] = f2bf(fmaxf((x[i + q + 1] - mean) * rstd * gv.y + ev.y, 0.f));
                y[q + 2] = f2bf(fmaxf((x[i + q + 2] - mean) * rstd * gv.z + ev.z, 0.f));
                y[q + 3] = f2bf(fmaxf((x[i + q + 3] - mean) * rstd * gv.w + ev.w, 0.f));
            }
            uint4 wv;
            wv.x = (uint32_t)y[0] | ((uint32_t)y[1] << 16);
            wv.y = (uint32_t)y[2] | ((uint32_t)y[3] << 16);
            wv.z = (uint32_t)y[4] | ((uint32_t)y[5] << 16);
            wv.w = (uint32_t)y[6] | ((uint32_t)y[7] << 16);
            int g = (c0 + i) >> 3;
            *(uint4*)&Asm[r * 512 + ((g ^ (r & 7)) * 8)] = wv;
        }
    }

    auto stageB = [&](int buf, int it) {
        #pragma unroll
        for (int j = 0; j < 4; ++j) {
            int G = j * 256 + tid;
            int row = G >> 2, g = G & 3;
            int colg = g ^ (row & 3);
            gl2lds16(W2t + ((size_t)t * HC + row) * H2C + it * 32 + colg * 8,
                     &Bsm[buf][(j * 256 + w * 64) * 8]);
        }
    };

    stageB(0, 0);
    __syncthreads();

    f32x4 acc[4];
    #pragma unroll
    for (int n = 0; n < 4; ++n) acc[n] = (f32x4){0.f, 0.f, 0.f, 0.f};

    for (int it = 0; it < 16; ++it) {
        if (it + 1 < 16) stageB((it + 1) & 1, it + 1);
        const unsigned short* Bs = &Bsm[it & 1][0];
        int g = lane >> 4;
        int arow = lane & 15;
        bf16x8 af = *(const bf16x8*)&Asm[arow * 512 + (((it * 4 + g) ^ (arow & 7)) * 8)];
        #pragma unroll
        for (int n = 0; n < 4; ++n) {
            int brow = w * 64 + n * 16 + arow;
            bf16x8 bv = *(const bf16x8*)&Bs[brow * 32 + ((g ^ (brow & 3)) * 8)];
            acc[n] = __builtin_amdgcn_mfma_f32_16x16x32_bf16(af, bv, acc[n], 0, 0, 0);
        }
        __syncthreads();
    }

    // ---- epilogue: LN2 + ReLU + weight-net dot + softmax + scatter ----
    float b2v[4], g2v[4], e2v[4];
    float4 wv[4];
    #pragma unroll
    for (int n = 0; n < 4; ++n) {
        int col = w * 64 + n * 16 + (lane & 15);
        b2v[n] = b2[t * HC + col];
        g2v[n] = g2[t * HC + col];
        e2v[n] = be2[t * HC + col];
        wv[n] = *(const float4*)&Ww[((size_t)t * H2C + col) * 4];
    }
    float s4[4], q4[4];
    #pragma unroll
    for (int j = 0; j < 4; ++j) {
        float s = 0.f, sq = 0.f;
        #pragma unroll
        for (int n = 0; n < 4; ++n) {
            float xv = acc[n][j] + b2v[n];
            s += xv; sq += xv * xv;
        }
        #pragma unroll
        for (int o = 1; o < 16; o <<= 1) { s += __shfl_xor(s, o); sq += __shfl_xor(sq, o); }
        s4[j] = s; q4[j] = sq;
    }
    if ((lane & 15) == 0) {
        #pragma unroll
        for (int j = 0; j < 4; ++j) {
            int r = (lane >> 4) * 4 + j;
            red[r][w][0] = s4[j];
            red[r][w][1] = q4[j];
        }
    }
    __syncthreads();
    float mean[4], rstd[4];
    #pragma unroll
    for (int j = 0; j < 4; ++j) {
        int r = (lane >> 4) * 4 + j;
        float S = red[r][0][0] + red[r][1][0] + red[r][2][0] + red[r][3][0];
        float SQ = red[r][0][1] + red[r][1][1] + red[r][2][1] + red[r][3][1];
        mean[j] = S * (1.f / HC);
        float var = SQ * (1.f / HC) - mean[j] * mean[j];
        rstd[j] = rsqrtf(var + 1e-5f);
    }
    float p[4][4];
    #pragma unroll
    for (int j = 0; j < 4; ++j) {
        p[j][0] = 0.f; p[j][1] = 0.f; p[j][2] = 0.f; p[j][3] = 0.f;
        #pragma unroll
        for (int n = 0; n < 4; ++n) {
            float yv = fmaxf((acc[n][j] + b2v[n] - mean[j]) * rstd[j] * g2v[n] + e2v[n], 0.f);
            p[j][0] += yv * wv[n].x; p[j][1] += yv * wv[n].y;
            p[j][2] += yv * wv[n].z; p[j][3] += yv * wv[n].w;
        }
        #pragma unroll
        for (int m = 0; m < 4; ++m)
            #pragma unroll
            for (int o = 1; o < 16; o <<= 1) p[j][m] += __shfl_xor(p[j][m], o);
    }
    __syncthreads();
    if ((lane & 15) == 0) {
        #pragma unroll
        for (int j = 0; j < 4; ++j) {
            int r = (lane >> 4) * 4 + j;
            red[r][w][0] = p[j][0]; red[r][w][1] = p[j][1];
            red[r][w][2] = p[j][2]; red[r][w][3] = p[j][3];
        }
    }
    __syncthreads();
    if (tid < 16 && tid < rows) {
        float raw[4];
        #pragma unroll
        for (int m = 0; m < 4; ++m)
            raw[m] = red[tid][0][m] + red[tid][1][m] + red[tid][2][m] + red[tid][3][m] + tb[t * 4 + m];
        float mx = fmaxf(fmaxf(raw[0], raw[1]), fmaxf(raw[2], raw[3]));
        float e0 = expf(raw[0] - mx), e1 = expf(raw[1] - mx);
        float e2 = expf(raw[2] - mx), e3 = expf(raw[3] - mx);
        float si = 1.f / (e0 + e1 + e2 + e3);
        *(float4*)(out + (size_t)order[prow + tid] * 4) = make_float4(e0 * si, e1 * si, e2 * si, e3 * si);
    }
}

extern "C" void kernel_launch(void* const* d_in, const int* in_sizes, int n_in,
                              void* d_out, int out_size, void* d_ws, size_t ws_size,
                              hipStream_t stream) {
    const float* f0 = (const float*)d_in[0];
    const float* f1 = (const float*)d_in[1];
    const float* f2 = (const float*)d_in[2];
    const float* f3 = (const float*)d_in[3];
    const float* W1 = (const float*)d_in[4];
    const float* b1 = (const float*)d_in[5];
    const float* g1 = (const float*)d_in[6];
    const float* be1 = (const float*)d_in[7];
    const float* W2 = (const float*)d_in[8];
    const float* b2 = (const float*)d_in[9];
    const float* g2 = (const float*)d_in[10];
    const float* be2 = (const float*)d_in[11];
    const float* temb = (const float*)d_in[12];
    const float* Ww = (const float*)d_in[13];
    const float* bw = (const float*)d_in[14];
    const int* task_ids = (const int*)d_in[15];
    float* out = (float*)d_out;

    char* ws = (char*)d_ws;
    size_t off = 0;
    auto walloc = [&](size_t bytes) -> void* {
        void* p = ws + off;
        off = (off + bytes + 255) & ~(size_t)255;
        return p;
    };
    float* tb = (float*)walloc(128);
    int* tiles = (int*)walloc(64 * 3 * 4);
    int* bmap = (int*)walloc(NWG1 * 4);
    int* tiles2 = (int*)walloc(272 * 3 * 4);
    int* ntile2 = (int*)walloc(4);
    int* order = (int*)walloc((size_t)B_N * 4);
    unsigned short* W1t = (unsigned short*)walloc((size_t)T_N * H2C * DIN * 2);
    unsigned short* W2t = (unsigned short*)walloc((size_t)T_N * HC * H2C * 2);
    unsigned short* h1p = (unsigned short*)walloc((size_t)SPLITK1 * B_N * H2C * 2);

    k_pre<<<4353, 256, 0, stream>>>(W1, W2, task_ids, temb, Ww, bw,
                                    W1t, W2t, order, tiles, bmap, tiles2, ntile2, tb);
    k_gemm1<<<NWG1, 256, 0, stream>>>(f0, f1, f2, f3, W1t, h1p, order, tiles, bmap);
    k_gemm2f<<<NWG2, 256, 0, stream>>>(h1p, W2t, b1, g1, be1, b2, g2, be2, Ww, tb,
                                       order, tiles2, ntile2, out);
}